// Round 6
// baseline (150.659 us; speedup 1.0000x reference)
//
#include <hip/hip_runtime.h>
#include <hip/hip_bf16.h>
#include <cstdint>

#define NHEADS 16
#define HDIM   64
#define BATCH  2
#define SEQ    2048
#define DMODEL 1024
#define MROWS  (BATCH * SEQ)   // 4096

using bf16 = __hip_bfloat16;
typedef __attribute__((ext_vector_type(8))) short bf16x8;
typedef __attribute__((ext_vector_type(4))) short bf16x4;
typedef __attribute__((ext_vector_type(4))) float f32x4;

// 0.125 (1/sqrt(64)) * log2(e): softmax in exp2 domain
#define C_SCALE 0.1803368801111f

__device__ __forceinline__ void gload_lds16(const bf16* g, bf16* l) {
  __builtin_amdgcn_global_load_lds(
      (const __attribute__((address_space(1))) unsigned int*)g,
      (__attribute__((address_space(3))) unsigned int*)l, 16, 0, 0);
}

__device__ __forceinline__ short bf16bits(float x) {
  __hip_bfloat16 h = __float2bfloat16(x);
  return *reinterpret_cast<short*>(&h);
}

// ---------- cast X fp32 -> bf16 ----------
__global__ __launch_bounds__(256) void cast_x_kernel(const float* __restrict__ in,
                                                     bf16* __restrict__ out) {
  const int i = (blockIdx.x * 256 + threadIdx.x) * 4;
  const float4 v = *reinterpret_cast<const float4*>(in + i);
  __hip_bfloat162 p0 = __float22bfloat162_rn(make_float2(v.x, v.y));
  __hip_bfloat162 p1 = __float22bfloat162_rn(make_float2(v.z, v.w));
  reinterpret_cast<__hip_bfloat162*>(out + i)[0] = p0;
  reinterpret_cast<__hip_bfloat162*>(out + i)[1] = p1;
}

// ---------- transpose-cast W [K][N] fp32 -> Wt [N][K] bf16 (3 mats via z) ----------
__global__ __launch_bounds__(256) void wtrans_kernel(const float* __restrict__ W0,
                                                     const float* __restrict__ W1,
                                                     const float* __restrict__ W2,
                                                     bf16* __restrict__ Wt) {
  __shared__ float tile[32][33];
  const float* W = (blockIdx.z == 0) ? W0 : ((blockIdx.z == 1) ? W1 : W2);
  bf16* out = Wt + (size_t)blockIdx.z * DMODEL * DMODEL;
  const int n0 = blockIdx.x * 32, k0 = blockIdx.y * 32;
  const int tx = threadIdx.x & 31, ty = threadIdx.x >> 5;  // 32 x 8
  #pragma unroll
  for (int r = 0; r < 32; r += 8)
    tile[ty + r][tx] = W[(size_t)(k0 + ty + r) * DMODEL + n0 + tx];
  __syncthreads();
  #pragma unroll
  for (int r = 0; r < 32; r += 8)
    out[(size_t)(n0 + ty + r) * DMODEL + k0 + tx] = __float2bfloat16(tile[tx][ty + r]);
}

// ---------- GEMM: C[M][N] = A[M][K] * Bt[N][K]^T ----------
// Triple-buffered BK=32 pipeline, counted vmcnt(4), one barrier per K-step.
// LDS layout [buf][kchunk][row][8 bf16]: fragment reads are 16 consecutive
// 16B chunks per 16 lanes -> bank-conflict-free; gload_lds dests linear.
template <int OUT_MODE>
__global__ __launch_bounds__(256, 3) void gemm_bt(const bf16* __restrict__ A,
                                                  const bf16* __restrict__ Bt, int Kdim,
                                                  bf16* __restrict__ q_out, bf16* __restrict__ k_out,
                                                  bf16* __restrict__ v_out,
                                                  float* __restrict__ f_out,
                                                  const float* __restrict__ bias, int Ndim,
                                                  int gx) {
  __shared__ __align__(16) bf16 Ab[3][4][128][8];
  __shared__ __align__(16) bf16 Bb[3][4][128][8];
  const int tid = threadIdx.x;
  const int lane = tid & 63, wave = tid >> 6;
  const int lr = lane & 15, lg = lane >> 4;
  // XCD swizzle (grid % 8 == 0): consecutive wgid within an XCD share the A-panel
  const int nwg = gridDim.x;
  const int wgid = (blockIdx.x & 7) * (nwg >> 3) + (blockIdx.x >> 3);
  const int by = wgid / gx, bx = wgid - by * gx;
  const int brow = by * 128, bcol = bx * 128;
  const int wr = (wave >> 1) * 64, wc = (wave & 1) * 64;
  f32x4 acc[4][4] = {};

  const int NT = Kdim >> 5;

  auto stage = [&](int t, int bb) {
    const int kb = t * 32;
    #pragma unroll
    for (int i = 0; i < 2; ++i) {
      const int o = i * 4096 + tid * 16;        // byte offset in 8 KB operand tile
      const int kc = o >> 11, row = (o >> 4) & 127;
      gload_lds16(A + (size_t)(brow + row) * Kdim + kb + kc * 8, &Ab[bb][kc][row][0]);
      gload_lds16(Bt + (size_t)(bcol + row) * Kdim + kb + kc * 8, &Bb[bb][kc][row][0]);
    }
  };

  stage(0, 0);
  stage(1, 1);
  asm volatile("s_waitcnt vmcnt(4)" ::: "memory");
  __builtin_amdgcn_s_barrier();

  int b0 = 0, b1 = 1, b2 = 2;  // b0 = current tile's buffer
  for (int t = 0; t < NT; ++t) {
    if (t + 2 < NT) stage(t + 2, b2);  // b2's readers (tile t-1) done at last barrier
    const bf16* Abase = &Ab[b0][0][0][0];
    const bf16* Bbase = &Bb[b0][0][0][0];
    bf16x8 af[4], bfr[4];
    #pragma unroll
    for (int ni = 0; ni < 4; ++ni)
      bfr[ni] = *(const bf16x8*)(Bbase + lg * 1024 + (wc + ni * 16 + lr) * 8);
    #pragma unroll
    for (int mi = 0; mi < 4; ++mi)
      af[mi] = *(const bf16x8*)(Abase + lg * 1024 + (wr + mi * 16 + lr) * 8);
    __builtin_amdgcn_s_setprio(1);
    #pragma unroll
    for (int mi = 0; mi < 4; ++mi)
      #pragma unroll
      for (int ni = 0; ni < 4; ++ni)
        acc[mi][ni] = __builtin_amdgcn_mfma_f32_16x16x32_bf16(af[mi], bfr[ni], acc[mi][ni], 0, 0, 0);
    __builtin_amdgcn_s_setprio(0);
    if (t + 2 < NT) asm volatile("s_waitcnt vmcnt(4)" ::: "memory");  // t+1 landed
    else            asm volatile("s_waitcnt vmcnt(0)" ::: "memory");
    __builtin_amdgcn_s_barrier();
    const int tmp = b0; b0 = b1; b1 = b2; b2 = tmp;
  }

  if (OUT_MODE == 0) {
    const int mat = bcol >> 10;  // 0:Q 1:K 2:V (block-uniform, 1024 % 128 == 0)
    const int cb = (bcol & 1023) + wc;
    if (mat < 2) {
      bf16* outm = (mat == 0) ? q_out : k_out;
      #pragma unroll
      for (int mi = 0; mi < 4; ++mi)
        #pragma unroll
        for (int ni = 0; ni < 4; ++ni)
          #pragma unroll
          for (int r = 0; r < 4; ++r) {
            const int m = brow + wr + mi * 16 + lg * 4 + r;
            const int c = cb + ni * 16 + lr;
            const int bb = m >> 11, n = m & 2047, hh = c >> 6, dh = c & 63;
            outm[((size_t)((bb * NHEADS + hh) * SEQ + n)) * HDIM + dh] =
                __float2bfloat16(acc[mi][ni][r]);
          }
    } else {
      // V^T: lane holds 4 consecutive n for fixed d -> 8B vector stores
      #pragma unroll
      for (int mi = 0; mi < 4; ++mi)
        #pragma unroll
        for (int ni = 0; ni < 4; ++ni) {
          const int mbase = brow + wr + mi * 16 + lg * 4;
          const int c = cb + ni * 16 + lr;
          const int bb = mbase >> 11, n0 = mbase & 2047, hh = c >> 6, dh = c & 63;
          ushort4 o;
          o.x = (unsigned short)bf16bits(acc[mi][ni][0]);
          o.y = (unsigned short)bf16bits(acc[mi][ni][1]);
          o.z = (unsigned short)bf16bits(acc[mi][ni][2]);
          o.w = (unsigned short)bf16bits(acc[mi][ni][3]);
          *reinterpret_cast<ushort4*>(
              &v_out[((size_t)((bb * NHEADS + hh) * HDIM + dh)) * SEQ + n0]) = o;
        }
    }
  } else {
    #pragma unroll
    for (int mi = 0; mi < 4; ++mi)
      #pragma unroll
      for (int ni = 0; ni < 4; ++ni)
        #pragma unroll
        for (int r = 0; r < 4; ++r) {
          const int m = brow + wr + mi * 16 + lg * 4 + r;
          const int c = bcol + wc + ni * 16 + lr;
          f_out[(size_t)m * Ndim + c] = acc[mi][ni][r] + bias[c];
        }
  }
}

// ---------- online-softmax update for one task (static loops, exact defer-max) ----------
template <bool TAIL>
__device__ __forceinline__ void sm_one(f32x4* s, int kbase, int qg, int lg,
                                       float& m, float& l, bf16x4* pb, f32x4* oacc) {
  float mloc[8];
  #pragma unroll
  for (int ni = 0; ni < 8; ++ni) {
    #pragma unroll
    for (int r = 0; r < 4; ++r) {
      float v = s[ni][r] * C_SCALE;
      if (TAIL) {
        if (kbase + ni * 16 + lg * 4 + r > qg) v = -3e38f;
      }
      s[ni][r] = v;
    }
    mloc[ni] = fmaxf(fmaxf(s[ni][0], s[ni][1]), fmaxf(s[ni][2], s[ni][3]));
  }
  float mx = fmaxf(fmaxf(fmaxf(mloc[0], mloc[1]), fmaxf(mloc[2], mloc[3])),
                   fmaxf(fmaxf(mloc[4], mloc[5]), fmaxf(mloc[6], mloc[7])));
  mx = fmaxf(mx, __shfl_xor(mx, 16, 64));
  mx = fmaxf(mx, __shfl_xor(mx, 32, 64));
  if (!__all(mx <= m)) {  // wave-uniform; skip is EXACT (sc==1)
    const float mnew = fmaxf(m, mx);
    const float sc = __builtin_amdgcn_exp2f(m - mnew);
    m = mnew;
    l *= sc;
    #pragma unroll
    for (int nj = 0; nj < 4; ++nj)
      #pragma unroll
      for (int r = 0; r < 4; ++r) oacc[nj][r] *= sc;
  }
  float rl[8];
  #pragma unroll
  for (int ni = 0; ni < 8; ++ni) {
    const float p0 = __builtin_amdgcn_exp2f(s[ni][0] - m);
    const float p1 = __builtin_amdgcn_exp2f(s[ni][1] - m);
    const float p2 = __builtin_amdgcn_exp2f(s[ni][2] - m);
    const float p3 = __builtin_amdgcn_exp2f(s[ni][3] - m);
    pb[ni][0] = bf16bits(p0); pb[ni][1] = bf16bits(p1);
    pb[ni][2] = bf16bits(p2); pb[ni][3] = bf16bits(p3);
    rl[ni] = (p0 + p1) + (p2 + p3);
  }
  float rs = ((rl[0] + rl[1]) + (rl[2] + rl[3])) + ((rl[4] + rl[5]) + (rl[6] + rl[7]));
  rs += __shfl_xor(rs, 16, 64);
  rs += __shfl_xor(rs, 32, 64);
  l += rs;
}

// ---------- one 128-key tile for the task pair: shared K/V fragments, 2x ILP ----------
template <bool HASA, bool TAILA, bool TAILB>
__device__ __forceinline__ void tile_pair(const bf16* __restrict__ Kb,
                                          const bf16* __restrict__ Vb, int kbase,
                                          int qgA, int qgB, int lr, int lg,
                                          const bf16x8* qfA, const bf16x8* qfB,
                                          f32x4* oaccA, f32x4* oaccB,
                                          float& mA, float& lA, float& mB, float& lB) {
  f32x4 sA[8], sB[8];
  #pragma unroll
  for (int ni = 0; ni < 8; ++ni) {
    const int row = ni * 16 + lr;
    const int sw = (row & 7) << 3;
    const bf16x8 kf0 = *(const bf16x8*)&Kb[row * 64 + ((lg * 8) ^ sw)];
    const bf16x8 kf1 = *(const bf16x8*)&Kb[row * 64 + ((32 + lg * 8) ^ sw)];
    f32x4 b = {};
    b = __builtin_amdgcn_mfma_f32_16x16x32_bf16(kf0, qfB[0], b, 0, 0, 0);
    b = __builtin_amdgcn_mfma_f32_16x16x32_bf16(kf1, qfB[1], b, 0, 0, 0);
    sB[ni] = b;
    if (HASA) {
      f32x4 a = {};
      a = __builtin_amdgcn_mfma_f32_16x16x32_bf16(kf0, qfA[0], a, 0, 0, 0);
      a = __builtin_amdgcn_mfma_f32_16x16x32_bf16(kf1, qfA[1], a, 0, 0, 0);
      sA[ni] = a;
    }
  }
  bf16x4 pbA[8], pbB[8];
  sm_one<TAILB>(sB, kbase, qgB, lg, mB, lB, pbB, oaccB);
  if (HASA) sm_one<TAILA>(sA, kbase, qgA, lg, mA, lA, pbA, oaccA);
  #pragma unroll
  for (int ni = 0; ni < 8; ++ni)
    #pragma unroll
    for (int nj = 0; nj < 4; ++nj) {
      const int d = nj * 16 + lr;
      const bf16x4 vf = *(const bf16x4*)&Vb[d * 128 + ((ni * 16 + lg * 4) ^ ((d & 15) << 3))];
      oaccB[nj] = __builtin_amdgcn_mfma_f32_16x16x16bf16_1k(vf, pbB[ni], oaccB[nj], 0, 0, 0);
      if (HASA)
        oaccA[nj] = __builtin_amdgcn_mfma_f32_16x16x16bf16_1k(vf, pbA[ni], oaccA[nj], 0, 0, 0);
    }
}

// ---------- causal flash attention: LDS-staged, task-pair merged, XCD-local ----------
__global__ __launch_bounds__(256, 2) void attn_kernel(const bf16* __restrict__ Qh,
                                                      const bf16* __restrict__ Kh,
                                                      const bf16* __restrict__ Vt,
                                                      bf16* __restrict__ Ctx) {
  __shared__ __align__(16) bf16 Kl[2][8192];  // [128 rows][64] swizzled (chunk ^= row&7)
  __shared__ __align__(16) bf16 Vl[2][8192];  // [64 rows][128] swizzled (chunk ^= row&15)

  // XCD swizzle: all 16 blocks of group g land on XCD g&7 (bid%8 round-robin)
  const int bid = blockIdx.x;
  const int x = bid & 7, sblk = bid >> 3;
  const int g = (sblk >> 4) * 8 + x;    // (b,h) group 0..31
  const int local = sblk & 15;
  const int tid = threadIdx.x, lane = tid & 63, wave = tid >> 6;
  const int lr = lane & 15, lg = lane >> 4;
  const int pid = local * 4 + wave;     // 0..63
  const int b = g >> 4, h = g & 15;
  const size_t headoff = (size_t)g * SEQ * HDIM;
  const bf16* Qp = Qh + headoff;
  const bf16* Kp = Kh + headoff;
  const bf16* Vp = Vt + headoff;

  const int tiA = pid, tiB = 127 - pid;
  const int TA = tiA >> 3, TB = tiB >> 3;  // both block-uniform; TA < TB always
  const int qA0 = tiA * 16, qB0 = tiB * 16;
  const int qgA = qA0 + lr, qgB = qB0 + lr;

  bf16x8 qfA[2], qfB[2];
  #pragma unroll
  for (int ks = 0; ks < 2; ++ks) {
    qfA[ks] = *(const bf16x8*)&Qp[(size_t)(qA0 + lr) * HDIM + ks * 32 + lg * 8];
    qfB[ks] = *(const bf16x8*)&Qp[(size_t)(qB0 + lr) * HDIM + ks * 32 + lg * 8];
  }

  f32x4 oaccA[4] = {}, oaccB[4] = {};
  float mA = -3e38f, lA = 0.f, mB = -3e38f, lB = 0.f;

  // stage tile t (128 keys) into buffer bb; inverse-swizzled global source (rule #21)
  auto stage = [&](int t, int bb) {
    const int k0 = t * 128;
    #pragma unroll
    for (int i = 0; i < 4; ++i) {
      const int o = i * 4096 + tid * 16;  // byte offset in 16 KB buffer
      {  // K: rows of 128B, chunk ^= row&7
        const int row = o >> 7, slot = (o >> 4) & 7;
        const int scol = slot ^ (row & 7);
        gload_lds16(Kp + (size_t)(k0 + row) * HDIM + scol * 8, &Kl[bb][o >> 1]);
      }
      {  // V: rows of 256B, chunk ^= row&15
        const int row = o >> 8, slot = (o >> 4) & 15;
        const int scol = slot ^ (row & 15);
        gload_lds16(Vp + (size_t)row * SEQ + k0 + scol * 8, &Vl[bb][o >> 1]);
      }
    }
  };

  stage(0, 0);
  for (int t = 0; t <= TB; ++t) {
    const int cur = t & 1;
    if (t < TB) {
      stage(t + 1, cur ^ 1);
      asm volatile("s_waitcnt vmcnt(8)" ::: "memory");
    } else {
      asm volatile("s_waitcnt vmcnt(0)" ::: "memory");
    }
    __builtin_amdgcn_s_barrier();

    const bf16* Kb = &Kl[cur][0];
    const bf16* Vb = &Vl[cur][0];
    const int kbase = t * 128;

    // block-uniform dispatch; TA < TB guaranteed
    if (t < TA)
      tile_pair<true, false, false>(Kb, Vb, kbase, qgA, qgB, lr, lg, qfA, qfB,
                                    oaccA, oaccB, mA, lA, mB, lB);
    else if (t == TA)
      tile_pair<true, true, false>(Kb, Vb, kbase, qgA, qgB, lr, lg, qfA, qfB,
                                   oaccA, oaccB, mA, lA, mB, lB);
    else if (t < TB)
      tile_pair<false, false, false>(Kb, Vb, kbase, qgA, qgB, lr, lg, qfA, qfB,
                                     oaccA, oaccB, mA, lA, mB, lB);
    else
      tile_pair<false, false, true>(Kb, Vb, kbase, qgA, qgB, lr, lg, qfA, qfB,
                                    oaccA, oaccB, mA, lA, mB, lB);

    __builtin_amdgcn_s_barrier();
  }

  // write out both tasks
  #pragma unroll
  for (int task = 0; task < 2; ++task) {
    const f32x4* oacc = task ? oaccB : oaccA;
    const float rl = 1.0f / (task ? lB : lA);
    const int q0 = task ? qB0 : qA0;
    const int mrow = b * SEQ + q0 + lr;
    #pragma unroll
    for (int nj = 0; nj < 4; ++nj) {
      ushort4 o;
      o.x = (unsigned short)bf16bits(oacc[nj][0] * rl);
      o.y = (unsigned short)bf16bits(oacc[nj][1] * rl);
      o.z = (unsigned short)bf16bits(oacc[nj][2] * rl);
      o.w = (unsigned short)bf16bits(oacc[nj][3] * rl);
      *reinterpret_cast<ushort4*>(&Ctx[(size_t)mrow * DMODEL + h * HDIM + nj * 16 + lg * 4]) = o;
    }
  }
}

extern "C" void kernel_launch(void* const* d_in, const int* in_sizes, int n_in,
                              void* d_out, int out_size, void* d_ws, size_t ws_size,
                              hipStream_t stream) {
  const float* X  = (const float*)d_in[0];
  const float* Wq = (const float*)d_in[1];
  const float* Wk = (const float*)d_in[2];
  const float* Wv = (const float*)d_in[3];
  const float* Wo = (const float*)d_in[4];
  const float* bo = (const float*)d_in[5];
  float* out = (float*)d_out;

  char* p = (char*)d_ws;
  bf16* Xb   = (bf16*)p; p += (size_t)MROWS * DMODEL * 2;       // 8 MB
  bf16* Wqkv = (bf16*)p; p += (size_t)3 * DMODEL * DMODEL * 2;  // 6 MB  [3072][1024]
  bf16* Wot  = (bf16*)p; p += (size_t)DMODEL * DMODEL * 2;      // 2 MB
  bf16* Qh   = (bf16*)p; p += (size_t)MROWS * DMODEL * 2;       // 8 MB
  bf16* Kh   = (bf16*)p; p += (size_t)MROWS * DMODEL * 2;       // 8 MB
  bf16* Vt   = (bf16*)p; p += (size_t)MROWS * DMODEL * 2;       // 8 MB
  bf16* Ctx  = (bf16*)p; p += (size_t)MROWS * DMODEL * 2;       // 8 MB

  cast_x_kernel<<<(MROWS * DMODEL) / 1024, 256, 0, stream>>>(X, Xb);
  dim3 tg(32, 32, 3);
  wtrans_kernel<<<tg, 256, 0, stream>>>(Wq, Wk, Wv, Wqkv);
  dim3 tg1(32, 32, 1);
  wtrans_kernel<<<tg1, 256, 0, stream>>>(Wo, Wo, Wo, Wot);

  gemm_bt<0><<<768, 256, 0, stream>>>(Xb, Wqkv, DMODEL, Qh, Kh, Vt, nullptr, nullptr, 3072, 24);

  attn_kernel<<<512, 256, 0, stream>>>(Qh, Kh, Vt, Ctx);

  gemm_bt<1><<<256, 256, 0, stream>>>(Ctx, Wot, DMODEL, nullptr, nullptr, nullptr, out, bo, DMODEL, 8);
}

// Round 7
// 149.684 us; speedup vs baseline: 1.0065x; 1.0065x over previous
//
#include <hip/hip_runtime.h>
#include <hip/hip_bf16.h>
#include <cstdint>

#define NHEADS 16
#define HDIM   64
#define BATCH  2
#define SEQ    2048
#define DMODEL 1024
#define MROWS  (BATCH * SEQ)   // 4096

using bf16 = __hip_bfloat16;
typedef __attribute__((ext_vector_type(8))) short bf16x8;
typedef __attribute__((ext_vector_type(4))) short bf16x4;
typedef __attribute__((ext_vector_type(4))) float f32x4;

// 0.125 (1/sqrt(64)) * log2(e): softmax in exp2 domain
#define C_SCALE 0.1803368801111f

__device__ __forceinline__ void gload_lds16(const bf16* g, bf16* l) {
  __builtin_amdgcn_global_load_lds(
      (const __attribute__((address_space(1))) unsigned int*)g,
      (__attribute__((address_space(3))) unsigned int*)l, 16, 0, 0);
}

__device__ __forceinline__ short bf16bits(float x) {
  __hip_bfloat16 h = __float2bfloat16(x);
  return *reinterpret_cast<short*>(&h);
}

// ---------- cast X fp32 -> bf16 ----------
__global__ __launch_bounds__(256) void cast_x_kernel(const float* __restrict__ in,
                                                     bf16* __restrict__ out) {
  const int i = (blockIdx.x * 256 + threadIdx.x) * 4;
  const float4 v = *reinterpret_cast<const float4*>(in + i);
  __hip_bfloat162 p0 = __float22bfloat162_rn(make_float2(v.x, v.y));
  __hip_bfloat162 p1 = __float22bfloat162_rn(make_float2(v.z, v.w));
  reinterpret_cast<__hip_bfloat162*>(out + i)[0] = p0;
  reinterpret_cast<__hip_bfloat162*>(out + i)[1] = p1;
}

// ---------- transpose-cast W [K][N] fp32 -> Wt [N][K] bf16 (3 mats via z) ----------
__global__ __launch_bounds__(256) void wtrans_kernel(const float* __restrict__ W0,
                                                     const float* __restrict__ W1,
                                                     const float* __restrict__ W2,
                                                     bf16* __restrict__ Wt) {
  __shared__ float tile[32][33];
  const float* W = (blockIdx.z == 0) ? W0 : ((blockIdx.z == 1) ? W1 : W2);
  bf16* out = Wt + (size_t)blockIdx.z * DMODEL * DMODEL;
  const int n0 = blockIdx.x * 32, k0 = blockIdx.y * 32;
  const int tx = threadIdx.x & 31, ty = threadIdx.x >> 5;  // 32 x 8
  #pragma unroll
  for (int r = 0; r < 32; r += 8)
    tile[ty + r][tx] = W[(size_t)(k0 + ty + r) * DMODEL + n0 + tx];
  __syncthreads();
  #pragma unroll
  for (int r = 0; r < 32; r += 8)
    out[(size_t)(n0 + ty + r) * DMODEL + k0 + tx] = __float2bfloat16(tile[tx][ty + r]);
}

// ---------- GEMM: C[M][N] = A[M][K] * Bt[N][K]^T ----------
// m97-structure: single-buffered BK=64 tile, __syncthreads drains, compiler
// schedules all waits. LDS layout [kchunk][row][8 bf16]: fragment reads are
// 16 consecutive 16B chunks per 16-lane group -> bank-conflict-free; linear
// gload_lds destinations (rule #21 trivially satisfied).
template <int OUT_MODE>
__global__ __launch_bounds__(256, 3) void gemm_bt(const bf16* __restrict__ A,
                                                  const bf16* __restrict__ Bt, int Kdim,
                                                  bf16* __restrict__ q_out, bf16* __restrict__ k_out,
                                                  bf16* __restrict__ v_out,
                                                  float* __restrict__ f_out,
                                                  const float* __restrict__ bias, int Ndim) {
  __shared__ __align__(16) bf16 Ab[8][128][8];
  __shared__ __align__(16) bf16 Bb[8][128][8];
  const int tid = threadIdx.x;
  const int lane = tid & 63, wave = tid >> 6;
  const int lr = lane & 15, lg = lane >> 4;
  const int brow = blockIdx.y * 128, bcol = blockIdx.x * 128;
  const int wr = (wave >> 1) * 64, wc = (wave & 1) * 64;
  f32x4 acc[4][4] = {};

  const int srow = tid & 127, skc = tid >> 7;  // stage row / chunk-parity

  for (int kb = 0; kb < Kdim; kb += 64) {
    #pragma unroll
    for (int i = 0; i < 4; ++i) {
      const int kc = i * 2 + skc;
      gload_lds16(A + (size_t)(brow + srow) * Kdim + kb + kc * 8, &Ab[kc][srow][0]);
      gload_lds16(Bt + (size_t)(bcol + srow) * Kdim + kb + kc * 8, &Bb[kc][srow][0]);
    }
    __syncthreads();
    #pragma unroll
    for (int kw = 0; kw < 2; ++kw) {
      bf16x8 af[4], bfr[4];
      #pragma unroll
      for (int ni = 0; ni < 4; ++ni)
        bfr[ni] = *(const bf16x8*)&Bb[kw * 4 + lg][wc + ni * 16 + lr][0];
      #pragma unroll
      for (int mi = 0; mi < 4; ++mi)
        af[mi] = *(const bf16x8*)&Ab[kw * 4 + lg][wr + mi * 16 + lr][0];
      #pragma unroll
      for (int mi = 0; mi < 4; ++mi)
        #pragma unroll
        for (int ni = 0; ni < 4; ++ni)
          acc[mi][ni] = __builtin_amdgcn_mfma_f32_16x16x32_bf16(af[mi], bfr[ni], acc[mi][ni], 0, 0, 0);
    }
    __syncthreads();
  }

  if (OUT_MODE == 0) {
    const int mat = bcol >> 10;  // 0:Q 1:K 2:V (block-uniform, 1024 % 128 == 0)
    const int cb = (bcol & 1023) + wc;
    if (mat < 2) {
      bf16* outm = (mat == 0) ? q_out : k_out;
      #pragma unroll
      for (int mi = 0; mi < 4; ++mi)
        #pragma unroll
        for (int ni = 0; ni < 4; ++ni)
          #pragma unroll
          for (int r = 0; r < 4; ++r) {
            const int m = brow + wr + mi * 16 + lg * 4 + r;
            const int c = cb + ni * 16 + lr;
            const int bb = m >> 11, n = m & 2047, hh = c >> 6, dh = c & 63;
            outm[((size_t)((bb * NHEADS + hh) * SEQ + n)) * HDIM + dh] =
                __float2bfloat16(acc[mi][ni][r]);
          }
    } else {
      // V^T: lane holds 4 consecutive n for fixed d -> 8B vector stores
      #pragma unroll
      for (int mi = 0; mi < 4; ++mi)
        #pragma unroll
        for (int ni = 0; ni < 4; ++ni) {
          const int mbase = brow + wr + mi * 16 + lg * 4;
          const int c = cb + ni * 16 + lr;
          const int bb = mbase >> 11, n0 = mbase & 2047, hh = c >> 6, dh = c & 63;
          ushort4 o;
          o.x = (unsigned short)bf16bits(acc[mi][ni][0]);
          o.y = (unsigned short)bf16bits(acc[mi][ni][1]);
          o.z = (unsigned short)bf16bits(acc[mi][ni][2]);
          o.w = (unsigned short)bf16bits(acc[mi][ni][3]);
          *reinterpret_cast<ushort4*>(
              &v_out[((size_t)((bb * NHEADS + hh) * HDIM + dh)) * SEQ + n0]) = o;
        }
    }
  } else {
    #pragma unroll
    for (int mi = 0; mi < 4; ++mi)
      #pragma unroll
      for (int ni = 0; ni < 4; ++ni)
        #pragma unroll
        for (int r = 0; r < 4; ++r) {
          const int m = brow + wr + mi * 16 + lg * 4 + r;
          const int c = bcol + wc + ni * 16 + lr;
          f_out[(size_t)m * Ndim + c] = acc[mi][ni][r] + bias[c];
        }
  }
}

// ---------- online-softmax update for one task (static loops, exact defer-max) ----------
template <bool TAIL>
__device__ __forceinline__ void sm_one(f32x4* s, int kbase, int qg, int lg,
                                       float& m, float& l, bf16x4* pb, f32x4* oacc) {
  float mloc[8];
  #pragma unroll
  for (int ni = 0; ni < 8; ++ni) {
    #pragma unroll
    for (int r = 0; r < 4; ++r) {
      float v = s[ni][r] * C_SCALE;
      if (TAIL) {
        if (kbase + ni * 16 + lg * 4 + r > qg) v = -3e38f;
      }
      s[ni][r] = v;
    }
    mloc[ni] = fmaxf(fmaxf(s[ni][0], s[ni][1]), fmaxf(s[ni][2], s[ni][3]));
  }
  float mx = fmaxf(fmaxf(fmaxf(mloc[0], mloc[1]), fmaxf(mloc[2], mloc[3])),
                   fmaxf(fmaxf(mloc[4], mloc[5]), fmaxf(mloc[6], mloc[7])));
  mx = fmaxf(mx, __shfl_xor(mx, 16, 64));
  mx = fmaxf(mx, __shfl_xor(mx, 32, 64));
  if (!__all(mx <= m)) {  // wave-uniform; skip is EXACT (sc==1)
    const float mnew = fmaxf(m, mx);
    const float sc = __builtin_amdgcn_exp2f(m - mnew);
    m = mnew;
    l *= sc;
    #pragma unroll
    for (int nj = 0; nj < 4; ++nj)
      #pragma unroll
      for (int r = 0; r < 4; ++r) oacc[nj][r] *= sc;
  }
  float rl[8];
  #pragma unroll
  for (int ni = 0; ni < 8; ++ni) {
    const float p0 = __builtin_amdgcn_exp2f(s[ni][0] - m);
    const float p1 = __builtin_amdgcn_exp2f(s[ni][1] - m);
    const float p2 = __builtin_amdgcn_exp2f(s[ni][2] - m);
    const float p3 = __builtin_amdgcn_exp2f(s[ni][3] - m);
    pb[ni][0] = bf16bits(p0); pb[ni][1] = bf16bits(p1);
    pb[ni][2] = bf16bits(p2); pb[ni][3] = bf16bits(p3);
    rl[ni] = (p0 + p1) + (p2 + p3);
  }
  float rs = ((rl[0] + rl[1]) + (rl[2] + rl[3])) + ((rl[4] + rl[5]) + (rl[6] + rl[7]));
  rs += __shfl_xor(rs, 16, 64);
  rs += __shfl_xor(rs, 32, 64);
  l += rs;
}

// ---------- one 128-key tile for the task pair: shared K/V fragments, 2x ILP ----------
template <bool HASA, bool TAILA, bool TAILB>
__device__ __forceinline__ void tile_pair(const bf16* __restrict__ Kb,
                                          const bf16* __restrict__ Vb, int kbase,
                                          int qgA, int qgB, int lr, int lg,
                                          const bf16x8* qfA, const bf16x8* qfB,
                                          f32x4* oaccA, f32x4* oaccB,
                                          float& mA, float& lA, float& mB, float& lB) {
  f32x4 sA[8], sB[8];
  #pragma unroll
  for (int ni = 0; ni < 8; ++ni) {
    const int row = ni * 16 + lr;
    const int sw = (row & 7) << 3;
    const bf16x8 kf0 = *(const bf16x8*)&Kb[row * 64 + ((lg * 8) ^ sw)];
    const bf16x8 kf1 = *(const bf16x8*)&Kb[row * 64 + ((32 + lg * 8) ^ sw)];
    f32x4 b = {};
    b = __builtin_amdgcn_mfma_f32_16x16x32_bf16(kf0, qfB[0], b, 0, 0, 0);
    b = __builtin_amdgcn_mfma_f32_16x16x32_bf16(kf1, qfB[1], b, 0, 0, 0);
    sB[ni] = b;
    if (HASA) {
      f32x4 a = {};
      a = __builtin_amdgcn_mfma_f32_16x16x32_bf16(kf0, qfA[0], a, 0, 0, 0);
      a = __builtin_amdgcn_mfma_f32_16x16x32_bf16(kf1, qfA[1], a, 0, 0, 0);
      sA[ni] = a;
    }
  }
  bf16x4 pbA[8], pbB[8];
  sm_one<TAILB>(sB, kbase, qgB, lg, mB, lB, pbB, oaccB);
  if (HASA) sm_one<TAILA>(sA, kbase, qgA, lg, mA, lA, pbA, oaccA);
  #pragma unroll
  for (int ni = 0; ni < 8; ++ni)
    #pragma unroll
    for (int nj = 0; nj < 4; ++nj) {
      const int d = nj * 16 + lr;
      const bf16x4 vf = *(const bf16x4*)&Vb[d * 128 + ((ni * 16 + lg * 4) ^ ((d & 15) << 3))];
      oaccB[nj] = __builtin_amdgcn_mfma_f32_16x16x16bf16_1k(vf, pbB[ni], oaccB[nj], 0, 0, 0);
      if (HASA)
        oaccA[nj] = __builtin_amdgcn_mfma_f32_16x16x16bf16_1k(vf, pbA[ni], oaccA[nj], 0, 0, 0);
    }
}

// ---------- causal flash attention: LDS-staged, task-pair merged, XCD-local ----------
__global__ __launch_bounds__(256, 2) void attn_kernel(const bf16* __restrict__ Qh,
                                                      const bf16* __restrict__ Kh,
                                                      const bf16* __restrict__ Vt,
                                                      bf16* __restrict__ Ctx) {
  __shared__ __align__(16) bf16 Kl[2][8192];  // [128 rows][64] swizzled (chunk ^= row&7)
  __shared__ __align__(16) bf16 Vl[2][8192];  // [64 rows][128] swizzled (chunk ^= row&15)

  // XCD swizzle: all 16 blocks of group g land on XCD g&7 (bid%8 round-robin)
  const int bid = blockIdx.x;
  const int x = bid & 7, sblk = bid >> 3;
  const int g = (sblk >> 4) * 8 + x;    // (b,h) group 0..31
  const int local = sblk & 15;
  const int tid = threadIdx.x, lane = tid & 63, wave = tid >> 6;
  const int lr = lane & 15, lg = lane >> 4;
  const int pid = local * 4 + wave;     // 0..63
  const int b = g >> 4, h = g & 15;
  const size_t headoff = (size_t)g * SEQ * HDIM;
  const bf16* Qp = Qh + headoff;
  const bf16* Kp = Kh + headoff;
  const bf16* Vp = Vt + headoff;

  const int tiA = pid, tiB = 127 - pid;
  const int TA = tiA >> 3, TB = tiB >> 3;  // both block-uniform; TA < TB always
  const int qA0 = tiA * 16, qB0 = tiB * 16;
  const int qgA = qA0 + lr, qgB = qB0 + lr;

  bf16x8 qfA[2], qfB[2];
  #pragma unroll
  for (int ks = 0; ks < 2; ++ks) {
    qfA[ks] = *(const bf16x8*)&Qp[(size_t)(qA0 + lr) * HDIM + ks * 32 + lg * 8];
    qfB[ks] = *(const bf16x8*)&Qp[(size_t)(qB0 + lr) * HDIM + ks * 32 + lg * 8];
  }

  f32x4 oaccA[4] = {}, oaccB[4] = {};
  float mA = -3e38f, lA = 0.f, mB = -3e38f, lB = 0.f;

  // stage tile t (128 keys) into buffer bb; inverse-swizzled global source (rule #21)
  auto stage = [&](int t, int bb) {
    const int k0 = t * 128;
    #pragma unroll
    for (int i = 0; i < 4; ++i) {
      const int o = i * 4096 + tid * 16;  // byte offset in 16 KB buffer
      {  // K: rows of 128B, chunk ^= row&7
        const int row = o >> 7, slot = (o >> 4) & 7;
        const int scol = slot ^ (row & 7);
        gload_lds16(Kp + (size_t)(k0 + row) * HDIM + scol * 8, &Kl[bb][o >> 1]);
      }
      {  // V: rows of 256B, chunk ^= row&15
        const int row = o >> 8, slot = (o >> 4) & 15;
        const int scol = slot ^ (row & 15);
        gload_lds16(Vp + (size_t)row * SEQ + k0 + scol * 8, &Vl[bb][o >> 1]);
      }
    }
  };

  stage(0, 0);
  for (int t = 0; t <= TB; ++t) {
    const int cur = t & 1;
    if (t < TB) {
      stage(t + 1, cur ^ 1);
      asm volatile("s_waitcnt vmcnt(8)" ::: "memory");
    } else {
      asm volatile("s_waitcnt vmcnt(0)" ::: "memory");
    }
    __builtin_amdgcn_s_barrier();

    const bf16* Kb = &Kl[cur][0];
    const bf16* Vb = &Vl[cur][0];
    const int kbase = t * 128;

    // block-uniform dispatch; TA < TB guaranteed
    if (t < TA)
      tile_pair<true, false, false>(Kb, Vb, kbase, qgA, qgB, lr, lg, qfA, qfB,
                                    oaccA, oaccB, mA, lA, mB, lB);
    else if (t == TA)
      tile_pair<true, true, false>(Kb, Vb, kbase, qgA, qgB, lr, lg, qfA, qfB,
                                   oaccA, oaccB, mA, lA, mB, lB);
    else if (t < TB)
      tile_pair<false, false, false>(Kb, Vb, kbase, qgA, qgB, lr, lg, qfA, qfB,
                                     oaccA, oaccB, mA, lA, mB, lB);
    else
      tile_pair<false, false, true>(Kb, Vb, kbase, qgA, qgB, lr, lg, qfA, qfB,
                                    oaccA, oaccB, mA, lA, mB, lB);

    __builtin_amdgcn_s_barrier();
  }

  // write out both tasks
  #pragma unroll
  for (int task = 0; task < 2; ++task) {
    const f32x4* oacc = task ? oaccB : oaccA;
    const float rl = 1.0f / (task ? lB : lA);
    const int q0 = task ? qB0 : qA0;
    const int mrow = b * SEQ + q0 + lr;
    #pragma unroll
    for (int nj = 0; nj < 4; ++nj) {
      ushort4 o;
      o.x = (unsigned short)bf16bits(oacc[nj][0] * rl);
      o.y = (unsigned short)bf16bits(oacc[nj][1] * rl);
      o.z = (unsigned short)bf16bits(oacc[nj][2] * rl);
      o.w = (unsigned short)bf16bits(oacc[nj][3] * rl);
      *reinterpret_cast<ushort4*>(&Ctx[(size_t)mrow * DMODEL + h * HDIM + nj * 16 + lg * 4]) = o;
    }
  }
}

extern "C" void kernel_launch(void* const* d_in, const int* in_sizes, int n_in,
                              void* d_out, int out_size, void* d_ws, size_t ws_size,
                              hipStream_t stream) {
  const float* X  = (const float*)d_in[0];
  const float* Wq = (const float*)d_in[1];
  const float* Wk = (const float*)d_in[2];
  const float* Wv = (const float*)d_in[3];
  const float* Wo = (const float*)d_in[4];
  const float* bo = (const float*)d_in[5];
  float* out = (float*)d_out;

  char* p = (char*)d_ws;
  bf16* Xb   = (bf16*)p; p += (size_t)MROWS * DMODEL * 2;       // 8 MB
  bf16* Wqkv = (bf16*)p; p += (size_t)3 * DMODEL * DMODEL * 2;  // 6 MB  [3072][1024]
  bf16* Wot  = (bf16*)p; p += (size_t)DMODEL * DMODEL * 2;      // 2 MB
  bf16* Qh   = (bf16*)p; p += (size_t)MROWS * DMODEL * 2;       // 8 MB
  bf16* Kh   = (bf16*)p; p += (size_t)MROWS * DMODEL * 2;       // 8 MB
  bf16* Vt   = (bf16*)p; p += (size_t)MROWS * DMODEL * 2;       // 8 MB
  bf16* Ctx  = (bf16*)p; p += (size_t)MROWS * DMODEL * 2;       // 8 MB

  cast_x_kernel<<<(MROWS * DMODEL) / 1024, 256, 0, stream>>>(X, Xb);
  dim3 tg(32, 32, 3);
  wtrans_kernel<<<tg, 256, 0, stream>>>(Wq, Wk, Wv, Wqkv);
  dim3 tg1(32, 32, 1);
  wtrans_kernel<<<tg1, 256, 0, stream>>>(Wo, Wo, Wo, Wot);

  dim3 g1(3072 / 128, MROWS / 128);  // 24 x 32
  gemm_bt<0><<<g1, 256, 0, stream>>>(Xb, Wqkv, DMODEL, Qh, Kh, Vt, nullptr, nullptr, 3072);

  attn_kernel<<<512, 256, 0, stream>>>(Qh, Kh, Vt, Ctx);

  dim3 g2(DMODEL / 128, MROWS / 128);  // 8 x 32
  gemm_bt<1><<<g2, 256, 0, stream>>>(Ctx, Wot, DMODEL, nullptr, nullptr, nullptr, out, bo, DMODEL);
}

// Round 8
// 117.437 us; speedup vs baseline: 1.2829x; 1.2746x over previous
//
#include <hip/hip_runtime.h>
#include <hip/hip_bf16.h>
#include <cstdint>

#define NHEADS 16
#define HDIM   64
#define BATCH  2
#define SEQ    2048
#define DMODEL 1024
#define MROWS  (BATCH * SEQ)   // 4096

using bf16 = __hip_bfloat16;
typedef __attribute__((ext_vector_type(8))) short bf16x8;
typedef __attribute__((ext_vector_type(4))) short bf16x4;
typedef __attribute__((ext_vector_type(4))) float f32x4;

// 0.125 (1/sqrt(64)) * log2(e): softmax in exp2 domain
#define C_SCALE 0.1803368801111f

__device__ __forceinline__ void gload_lds16(const bf16* g, bf16* l) {
  __builtin_amdgcn_global_load_lds(
      (const __attribute__((address_space(1))) unsigned int*)g,
      (__attribute__((address_space(3))) unsigned int*)l, 16, 0, 0);
}

__device__ __forceinline__ short bf16bits(float x) {
  __hip_bfloat16 h = __float2bfloat16(x);
  return *reinterpret_cast<short*>(&h);
}

// ---------- cast X fp32 -> bf16 ----------
__global__ __launch_bounds__(256) void cast_x_kernel(const float* __restrict__ in,
                                                     bf16* __restrict__ out) {
  const int i = (blockIdx.x * 256 + threadIdx.x) * 4;
  const float4 v = *reinterpret_cast<const float4*>(in + i);
  __hip_bfloat162 p0 = __float22bfloat162_rn(make_float2(v.x, v.y));
  __hip_bfloat162 p1 = __float22bfloat162_rn(make_float2(v.z, v.w));
  reinterpret_cast<__hip_bfloat162*>(out + i)[0] = p0;
  reinterpret_cast<__hip_bfloat162*>(out + i)[1] = p1;
}

// ---------- transpose-cast W [K][N] fp32 -> Wt [N][K] bf16 (3 mats via z) ----------
__global__ __launch_bounds__(256) void wtrans_kernel(const float* __restrict__ W0,
                                                     const float* __restrict__ W1,
                                                     const float* __restrict__ W2,
                                                     bf16* __restrict__ Wt) {
  __shared__ float tile[32][33];
  const float* W = (blockIdx.z == 0) ? W0 : ((blockIdx.z == 1) ? W1 : W2);
  bf16* out = Wt + (size_t)blockIdx.z * DMODEL * DMODEL;
  const int n0 = blockIdx.x * 32, k0 = blockIdx.y * 32;
  const int tx = threadIdx.x & 31, ty = threadIdx.x >> 5;  // 32 x 8
  #pragma unroll
  for (int r = 0; r < 32; r += 8)
    tile[ty + r][tx] = W[(size_t)(k0 + ty + r) * DMODEL + n0 + tx];
  __syncthreads();
  #pragma unroll
  for (int r = 0; r < 32; r += 8)
    out[(size_t)(n0 + ty + r) * DMODEL + k0 + tx] = __float2bfloat16(tile[tx][ty + r]);
}

// ---------- GEMM: C[M][N] = A[M][K] * Bt[N][K]^T ----------
// BK=32 double-buffered, counted vmcnt(4) (attn-proven skeleton).
// LDS row-major [128][32] with XOR swizzle slot^=(row>>1)&3: staging keeps
// lane-contiguous LDS dests + 64B-coalesced global reads (XOR permutes within
// a row's 64B only); fragment reads are ~2-way conflicts (free).
template <int OUT_MODE>
__global__ __launch_bounds__(256) void gemm_bt(const bf16* __restrict__ A,
                                               const bf16* __restrict__ Bt, int Kdim,
                                               bf16* __restrict__ q_out, bf16* __restrict__ k_out,
                                               bf16* __restrict__ v_out,
                                               float* __restrict__ f_out,
                                               const float* __restrict__ bias, int Ndim) {
  __shared__ __align__(16) bf16 Ab[2][128][32];
  __shared__ __align__(16) bf16 Bb[2][128][32];
  const int tid = threadIdx.x;
  const int lane = tid & 63, wave = tid >> 6;
  const int lr = lane & 15, lg = lane >> 4;
  const int brow = blockIdx.y * 128, bcol = blockIdx.x * 128;
  const int wr = (wave >> 1) * 64, wc = (wave & 1) * 64;
  f32x4 acc[4][4] = {};

  const int NT = Kdim >> 5;  // 32 K-steps

  auto stage = [&](int t, int bb) {
    const int kb = t * 32;
    #pragma unroll
    for (int i = 0; i < 2; ++i) {
      const int o = i * 4096 + tid * 16;           // byte offset in 8 KB tile
      const int row = o >> 6, slot = (o >> 4) & 3;
      const int scol = slot ^ ((row >> 1) & 3);    // pre-swizzled source
      gload_lds16(A + (size_t)(brow + row) * Kdim + kb + scol * 8, &Ab[bb][0][0] + (o >> 1));
      gload_lds16(Bt + (size_t)(bcol + row) * Kdim + kb + scol * 8, &Bb[bb][0][0] + (o >> 1));
    }
  };

  stage(0, 0);
  for (int t = 0; t < NT; ++t) {
    const int cur = t & 1;
    if (t + 1 < NT) {
      stage(t + 1, cur ^ 1);
      asm volatile("s_waitcnt vmcnt(4)" ::: "memory");  // tile t's 4 loads landed
    } else {
      asm volatile("s_waitcnt vmcnt(0)" ::: "memory");
    }
    __builtin_amdgcn_s_barrier();

    bf16x8 af[4], bfr[4];
    #pragma unroll
    for (int ni = 0; ni < 4; ++ni) {
      const int row = wc + ni * 16 + lr;
      bfr[ni] = *(const bf16x8*)&Bb[cur][row][(lg ^ ((row >> 1) & 3)) * 8];
    }
    #pragma unroll
    for (int mi = 0; mi < 4; ++mi) {
      const int row = wr + mi * 16 + lr;
      af[mi] = *(const bf16x8*)&Ab[cur][row][(lg ^ ((row >> 1) & 3)) * 8];
    }
    #pragma unroll
    for (int mi = 0; mi < 4; ++mi)
      #pragma unroll
      for (int ni = 0; ni < 4; ++ni)
        acc[mi][ni] = __builtin_amdgcn_mfma_f32_16x16x32_bf16(af[mi], bfr[ni], acc[mi][ni], 0, 0, 0);

    __builtin_amdgcn_s_barrier();
  }

  if (OUT_MODE == 0) {
    const int mat = bcol >> 10;  // 0:Q 1:K 2:V (block-uniform, 1024 % 128 == 0)
    const int cb = (bcol & 1023) + wc;
    if (mat < 2) {
      bf16* outm = (mat == 0) ? q_out : k_out;
      #pragma unroll
      for (int mi = 0; mi < 4; ++mi)
        #pragma unroll
        for (int ni = 0; ni < 4; ++ni)
          #pragma unroll
          for (int r = 0; r < 4; ++r) {
            const int m = brow + wr + mi * 16 + lg * 4 + r;
            const int c = cb + ni * 16 + lr;
            const int bb = m >> 11, n = m & 2047, hh = c >> 6, dh = c & 63;
            outm[((size_t)((bb * NHEADS + hh) * SEQ + n)) * HDIM + dh] =
                __float2bfloat16(acc[mi][ni][r]);
          }
    } else {
      // V^T: lane holds 4 consecutive n for fixed d -> 8B vector stores
      #pragma unroll
      for (int mi = 0; mi < 4; ++mi)
        #pragma unroll
        for (int ni = 0; ni < 4; ++ni) {
          const int mbase = brow + wr + mi * 16 + lg * 4;
          const int c = cb + ni * 16 + lr;
          const int bb = mbase >> 11, n0 = mbase & 2047, hh = c >> 6, dh = c & 63;
          ushort4 o;
          o.x = (unsigned short)bf16bits(acc[mi][ni][0]);
          o.y = (unsigned short)bf16bits(acc[mi][ni][1]);
          o.z = (unsigned short)bf16bits(acc[mi][ni][2]);
          o.w = (unsigned short)bf16bits(acc[mi][ni][3]);
          *reinterpret_cast<ushort4*>(
              &v_out[((size_t)((bb * NHEADS + hh) * HDIM + dh)) * SEQ + n0]) = o;
        }
    }
  } else {
    #pragma unroll
    for (int mi = 0; mi < 4; ++mi)
      #pragma unroll
      for (int ni = 0; ni < 4; ++ni)
        #pragma unroll
        for (int r = 0; r < 4; ++r) {
          const int m = brow + wr + mi * 16 + lg * 4 + r;
          const int c = bcol + wc + ni * 16 + lr;
          f_out[(size_t)m * Ndim + c] = acc[mi][ni][r] + bias[c];
        }
  }
}

// ---------- online-softmax update for one task (static loops, exact defer-max) ----------
template <bool TAIL>
__device__ __forceinline__ void sm_one(f32x4* s, int kbase, int qg, int lg,
                                       float& m, float& l, bf16x4* pb, f32x4* oacc) {
  float mloc[8];
  #pragma unroll
  for (int ni = 0; ni < 8; ++ni) {
    #pragma unroll
    for (int r = 0; r < 4; ++r) {
      float v = s[ni][r] * C_SCALE;
      if (TAIL) {
        if (kbase + ni * 16 + lg * 4 + r > qg) v = -3e38f;
      }
      s[ni][r] = v;
    }
    mloc[ni] = fmaxf(fmaxf(s[ni][0], s[ni][1]), fmaxf(s[ni][2], s[ni][3]));
  }
  float mx = fmaxf(fmaxf(fmaxf(mloc[0], mloc[1]), fmaxf(mloc[2], mloc[3])),
                   fmaxf(fmaxf(mloc[4], mloc[5]), fmaxf(mloc[6], mloc[7])));
  mx = fmaxf(mx, __shfl_xor(mx, 16, 64));
  mx = fmaxf(mx, __shfl_xor(mx, 32, 64));
  if (!__all(mx <= m)) {  // wave-uniform; skip is EXACT (sc==1)
    const float mnew = fmaxf(m, mx);
    const float sc = __builtin_amdgcn_exp2f(m - mnew);
    m = mnew;
    l *= sc;
    #pragma unroll
    for (int nj = 0; nj < 4; ++nj)
      #pragma unroll
      for (int r = 0; r < 4; ++r) oacc[nj][r] *= sc;
  }
  float rl[8];
  #pragma unroll
  for (int ni = 0; ni < 8; ++ni) {
    const float p0 = __builtin_amdgcn_exp2f(s[ni][0] - m);
    const float p1 = __builtin_amdgcn_exp2f(s[ni][1] - m);
    const float p2 = __builtin_amdgcn_exp2f(s[ni][2] - m);
    const float p3 = __builtin_amdgcn_exp2f(s[ni][3] - m);
    pb[ni][0] = bf16bits(p0); pb[ni][1] = bf16bits(p1);
    pb[ni][2] = bf16bits(p2); pb[ni][3] = bf16bits(p3);
    rl[ni] = (p0 + p1) + (p2 + p3);
  }
  float rs = ((rl[0] + rl[1]) + (rl[2] + rl[3])) + ((rl[4] + rl[5]) + (rl[6] + rl[7]));
  rs += __shfl_xor(rs, 16, 64);
  rs += __shfl_xor(rs, 32, 64);
  l += rs;
}

// ---------- one 128-key tile for the task pair: shared K/V fragments, 2x ILP ----------
template <bool HASA, bool TAILA, bool TAILB>
__device__ __forceinline__ void tile_pair(const bf16* __restrict__ Kb,
                                          const bf16* __restrict__ Vb, int kbase,
                                          int qgA, int qgB, int lr, int lg,
                                          const bf16x8* qfA, const bf16x8* qfB,
                                          f32x4* oaccA, f32x4* oaccB,
                                          float& mA, float& lA, float& mB, float& lB) {
  f32x4 sA[8], sB[8];
  #pragma unroll
  for (int ni = 0; ni < 8; ++ni) {
    const int row = ni * 16 + lr;
    const int sw = (row & 7) << 3;
    const bf16x8 kf0 = *(const bf16x8*)&Kb[row * 64 + ((lg * 8) ^ sw)];
    const bf16x8 kf1 = *(const bf16x8*)&Kb[row * 64 + ((32 + lg * 8) ^ sw)];
    f32x4 b = {};
    b = __builtin_amdgcn_mfma_f32_16x16x32_bf16(kf0, qfB[0], b, 0, 0, 0);
    b = __builtin_amdgcn_mfma_f32_16x16x32_bf16(kf1, qfB[1], b, 0, 0, 0);
    sB[ni] = b;
    if (HASA) {
      f32x4 a = {};
      a = __builtin_amdgcn_mfma_f32_16x16x32_bf16(kf0, qfA[0], a, 0, 0, 0);
      a = __builtin_amdgcn_mfma_f32_16x16x32_bf16(kf1, qfA[1], a, 0, 0, 0);
      sA[ni] = a;
    }
  }
  bf16x4 pbA[8], pbB[8];
  sm_one<TAILB>(sB, kbase, qgB, lg, mB, lB, pbB, oaccB);
  if (HASA) sm_one<TAILA>(sA, kbase, qgA, lg, mA, lA, pbA, oaccA);
  #pragma unroll
  for (int ni = 0; ni < 8; ++ni)
    #pragma unroll
    for (int nj = 0; nj < 4; ++nj) {
      const int d = nj * 16 + lr;
      const bf16x4 vf = *(const bf16x4*)&Vb[d * 128 + ((ni * 16 + lg * 4) ^ ((d & 15) << 3))];
      oaccB[nj] = __builtin_amdgcn_mfma_f32_16x16x16bf16_1k(vf, pbB[ni], oaccB[nj], 0, 0, 0);
      if (HASA)
        oaccA[nj] = __builtin_amdgcn_mfma_f32_16x16x16bf16_1k(vf, pbA[ni], oaccA[nj], 0, 0, 0);
    }
}

// ---------- causal flash attention: LDS-staged, task-pair merged, XCD-local ----------
__global__ __launch_bounds__(256, 2) void attn_kernel(const bf16* __restrict__ Qh,
                                                      const bf16* __restrict__ Kh,
                                                      const bf16* __restrict__ Vt,
                                                      bf16* __restrict__ Ctx) {
  __shared__ __align__(16) bf16 Kl[2][8192];  // [128 rows][64] swizzled (chunk ^= row&7)
  __shared__ __align__(16) bf16 Vl[2][8192];  // [64 rows][128] swizzled (chunk ^= row&15)

  // XCD swizzle: all 16 blocks of group g land on XCD g&7 (bid%8 round-robin)
  const int bid = blockIdx.x;
  const int x = bid & 7, sblk = bid >> 3;
  const int g = (sblk >> 4) * 8 + x;    // (b,h) group 0..31
  const int local = sblk & 15;
  const int tid = threadIdx.x, lane = tid & 63, wave = tid >> 6;
  const int lr = lane & 15, lg = lane >> 4;
  const int pid = local * 4 + wave;     // 0..63
  const int b = g >> 4, h = g & 15;
  const size_t headoff = (size_t)g * SEQ * HDIM;
  const bf16* Qp = Qh + headoff;
  const bf16* Kp = Kh + headoff;
  const bf16* Vp = Vt + headoff;

  const int tiA = pid, tiB = 127 - pid;
  const int TA = tiA >> 3, TB = tiB >> 3;  // both block-uniform; TA < TB always
  const int qA0 = tiA * 16, qB0 = tiB * 16;
  const int qgA = qA0 + lr, qgB = qB0 + lr;

  bf16x8 qfA[2], qfB[2];
  #pragma unroll
  for (int ks = 0; ks < 2; ++ks) {
    qfA[ks] = *(const bf16x8*)&Qp[(size_t)(qA0 + lr) * HDIM + ks * 32 + lg * 8];
    qfB[ks] = *(const bf16x8*)&Qp[(size_t)(qB0 + lr) * HDIM + ks * 32 + lg * 8];
  }

  f32x4 oaccA[4] = {}, oaccB[4] = {};
  float mA = -3e38f, lA = 0.f, mB = -3e38f, lB = 0.f;

  // stage tile t (128 keys) into buffer bb; inverse-swizzled global source (rule #21)
  auto stage = [&](int t, int bb) {
    const int k0 = t * 128;
    #pragma unroll
    for (int i = 0; i < 4; ++i) {
      const int o = i * 4096 + tid * 16;  // byte offset in 16 KB buffer
      {  // K: rows of 128B, chunk ^= row&7
        const int row = o >> 7, slot = (o >> 4) & 7;
        const int scol = slot ^ (row & 7);
        gload_lds16(Kp + (size_t)(k0 + row) * HDIM + scol * 8, &Kl[bb][o >> 1]);
      }
      {  // V: rows of 256B, chunk ^= row&15
        const int row = o >> 8, slot = (o >> 4) & 15;
        const int scol = slot ^ (row & 15);
        gload_lds16(Vp + (size_t)row * SEQ + k0 + scol * 8, &Vl[bb][o >> 1]);
      }
    }
  };

  stage(0, 0);
  for (int t = 0; t <= TB; ++t) {
    const int cur = t & 1;
    if (t < TB) {
      stage(t + 1, cur ^ 1);
      asm volatile("s_waitcnt vmcnt(8)" ::: "memory");
    } else {
      asm volatile("s_waitcnt vmcnt(0)" ::: "memory");
    }
    __builtin_amdgcn_s_barrier();

    const bf16* Kb = &Kl[cur][0];
    const bf16* Vb = &Vl[cur][0];
    const int kbase = t * 128;

    // block-uniform dispatch; TA < TB guaranteed
    if (t < TA)
      tile_pair<true, false, false>(Kb, Vb, kbase, qgA, qgB, lr, lg, qfA, qfB,
                                    oaccA, oaccB, mA, lA, mB, lB);
    else if (t == TA)
      tile_pair<true, true, false>(Kb, Vb, kbase, qgA, qgB, lr, lg, qfA, qfB,
                                   oaccA, oaccB, mA, lA, mB, lB);
    else if (t < TB)
      tile_pair<false, false, false>(Kb, Vb, kbase, qgA, qgB, lr, lg, qfA, qfB,
                                     oaccA, oaccB, mA, lA, mB, lB);
    else
      tile_pair<false, false, true>(Kb, Vb, kbase, qgA, qgB, lr, lg, qfA, qfB,
                                    oaccA, oaccB, mA, lA, mB, lB);

    __builtin_amdgcn_s_barrier();
  }

  // write out both tasks
  #pragma unroll
  for (int task = 0; task < 2; ++task) {
    const f32x4* oacc = task ? oaccB : oaccA;
    const float rl = 1.0f / (task ? lB : lA);
    const int q0 = task ? qB0 : qA0;
    const int mrow = b * SEQ + q0 + lr;
    #pragma unroll
    for (int nj = 0; nj < 4; ++nj) {
      ushort4 o;
      o.x = (unsigned short)bf16bits(oacc[nj][0] * rl);
      o.y = (unsigned short)bf16bits(oacc[nj][1] * rl);
      o.z = (unsigned short)bf16bits(oacc[nj][2] * rl);
      o.w = (unsigned short)bf16bits(oacc[nj][3] * rl);
      *reinterpret_cast<ushort4*>(&Ctx[(size_t)mrow * DMODEL + h * HDIM + nj * 16 + lg * 4]) = o;
    }
  }
}

extern "C" void kernel_launch(void* const* d_in, const int* in_sizes, int n_in,
                              void* d_out, int out_size, void* d_ws, size_t ws_size,
                              hipStream_t stream) {
  const float* X  = (const float*)d_in[0];
  const float* Wq = (const float*)d_in[1];
  const float* Wk = (const float*)d_in[2];
  const float* Wv = (const float*)d_in[3];
  const float* Wo = (const float*)d_in[4];
  const float* bo = (const float*)d_in[5];
  float* out = (float*)d_out;

  char* p = (char*)d_ws;
  bf16* Xb   = (bf16*)p; p += (size_t)MROWS * DMODEL * 2;       // 8 MB
  bf16* Wqkv = (bf16*)p; p += (size_t)3 * DMODEL * DMODEL * 2;  // 6 MB  [3072][1024]
  bf16* Wot  = (bf16*)p; p += (size_t)DMODEL * DMODEL * 2;      // 2 MB
  bf16* Qh   = (bf16*)p; p += (size_t)MROWS * DMODEL * 2;       // 8 MB
  bf16* Kh   = (bf16*)p; p += (size_t)MROWS * DMODEL * 2;       // 8 MB
  bf16* Vt   = (bf16*)p; p += (size_t)MROWS * DMODEL * 2;       // 8 MB
  bf16* Ctx  = (bf16*)p; p += (size_t)MROWS * DMODEL * 2;       // 8 MB

  cast_x_kernel<<<(MROWS * DMODEL) / 1024, 256, 0, stream>>>(X, Xb);
  dim3 tg(32, 32, 3);
  wtrans_kernel<<<tg, 256, 0, stream>>>(Wq, Wk, Wv, Wqkv);
  dim3 tg1(32, 32, 1);
  wtrans_kernel<<<tg1, 256, 0, stream>>>(Wo, Wo, Wo, Wot);

  dim3 g1(3072 / 128, MROWS / 128);  // 24 x 32
  gemm_bt<0><<<g1, 256, 0, stream>>>(Xb, Wqkv, DMODEL, Qh, Kh, Vt, nullptr, nullptr, 3072);

  attn_kernel<<<512, 256, 0, stream>>>(Qh, Kh, Vt, Ctx);

  dim3 g2(DMODEL / 128, MROWS / 128);  // 8 x 32
  gemm_bt<1><<<g2, 256, 0, stream>>>(Ctx, Wot, DMODEL, nullptr, nullptr, nullptr, out, bo, DMODEL);
}